// Round 4
// baseline (912.121 us; speedup 1.0000x reference)
//
#include <hip/hip_runtime.h>

#define Nn 100000
#define Ee 1600000
#define Ff 128
#define Gg 512
#define Cc 40
#define NCH 2048
#define CH  49   // ceil(Nn / NCH)

// ---------------- BN/bias folding: sc/sh per layer-feature ----------------
__global__ void prep_scales_k(const float* __restrict__ conv_b,
                              const float* __restrict__ gamma,
                              const float* __restrict__ beta,
                              const float* __restrict__ mean,
                              const float* __restrict__ var,
                              float* __restrict__ sc, float* __restrict__ sh)
{
    int i = blockIdx.x * blockDim.x + threadIdx.x;
    if (i >= 3 * Ff) return;
    float b = conv_b[i];
    if (i < 2 * Ff) {  // layers 0,1 have BN
        float s = gamma[i] * rsqrtf(var[i] + 1e-5f);
        sc[i] = s;
        sh[i] = (b - mean[i]) * s + beta[i];
    } else {           // layer 2: no BN
        sc[i] = 1.0f;
        sh[i] = b;
    }
}

// ---------------- CSR build ----------------
__global__ void count_edges_k(const int* __restrict__ dst, int* __restrict__ deg)
{
    int e = blockIdx.x * 256 + threadIdx.x;
    if (e < Ee) atomicAdd(&deg[dst[e]], 1);
}

__global__ void chunk_sum_k(const int* __restrict__ deg, int* __restrict__ csum)
{
    int t = blockIdx.x * 256 + threadIdx.x;
    if (t >= NCH) return;
    int i0 = t * CH, i1 = min(i0 + CH, Nn);
    int s = 0;
    for (int i = i0; i < i1; ++i) s += deg[i];
    csum[t] = s;
}

__global__ void scan_chunks_k(const int* __restrict__ csum, int* __restrict__ coff)
{
    __shared__ int tot[256];
    int t = threadIdx.x;
    int v[8]; int s = 0;
    #pragma unroll
    for (int j = 0; j < 8; ++j) { v[j] = csum[t * 8 + j]; s += v[j]; }
    tot[t] = s;
    __syncthreads();
    for (int d = 1; d < 256; d <<= 1) {
        int x = (t >= d) ? tot[t - d] : 0;
        __syncthreads();
        tot[t] += x;
        __syncthreads();
    }
    int base = tot[t] - s;  // exclusive prefix
    #pragma unroll
    for (int j = 0; j < 8; ++j) { coff[t * 8 + j] = base; base += v[j]; }
}

__global__ void write_offsets_k(const int* __restrict__ deg, const int* __restrict__ coff,
                                int* __restrict__ off, float* __restrict__ dinv)
{
    int t = blockIdx.x * 256 + threadIdx.x;
    if (t >= NCH) return;
    int i0 = t * CH, i1 = min(i0 + CH, Nn);
    int run = coff[t];
    for (int i = i0; i < i1; ++i) {
        off[i] = run;
        int d = deg[i];
        run += d;
        dinv[i] = rsqrtf((float)d + 1.0f);  // +1 self loop
    }
    if (t == 0) off[Nn] = Ee;
}

__global__ void fill_csr_k(const int* __restrict__ src, const int* __restrict__ dst,
                           const int* __restrict__ off, int* __restrict__ cur,
                           int* __restrict__ csrc)
{
    int e = blockIdx.x * 256 + threadIdx.x;
    if (e < Ee) {
        int d = dst[e];
        int p = off[d] + atomicAdd(&cur[d], 1);
        csrc[p] = src[e];
    }
}

// ---------------- GEMM v3: Y[r] = (A[r] @ W) * dinv[r] ----------------
// 256 thr = 128 rows x 2 col-halves. Each thread: 1 row, 64 cols.
// A row read once per col-half, k-chunked (32 floats = 8 float4) into regs so
// each 128B line is fully consumed while L1-resident. W via wave-uniform
// s_load (SGPR operand of v_fmac). No LDS, no barriers.
__global__ __launch_bounds__(256) void gemm_scale_k(
    const float* __restrict__ A, const float* __restrict__ W,
    const float* __restrict__ dinv, float* __restrict__ Y, int n)
{
    const int tid  = threadIdx.x;
    const int half = __builtin_amdgcn_readfirstlane(tid >> 7);  // wave-uniform
    const int cb   = half * 64;
    const int r    = blockIdx.x * 128 + (tid & 127);
    const int rr   = min(r, n - 1);
    const float4* Ap = (const float4*)(A + ((size_t)rr << 7));
    const float*  Wp = W + cb;

    float acc[64];
    #pragma unroll
    for (int c = 0; c < 64; ++c) acc[c] = 0.f;

    for (int kc = 0; kc < 4; ++kc) {          // k in chunks of 32
        float4 a[8];
        #pragma unroll
        for (int i = 0; i < 8; ++i) a[i] = Ap[kc * 8 + i];
        const float* af = reinterpret_cast<const float*>(a);
        #pragma unroll
        for (int kk = 0; kk < 32; ++kk) {
            const float av = af[kk];                       // static after unroll
            const float* wr = Wp + (kc * 32 + kk) * Ff;    // uniform -> s_load
            #pragma unroll
            for (int c = 0; c < 64; ++c)
                acc[c] = fmaf(av, wr[c], acc[c]);
        }
    }

    if (r < n) {
        const float di = dinv[r];
        float* yp = Y + ((size_t)r << 7) + cb;
        #pragma unroll
        for (int c = 0; c < 64; c += 4)
            *(float4*)(yp + c) = make_float4(acc[c] * di, acc[c + 1] * di,
                                             acc[c + 2] * di, acc[c + 3] * di);
    }
}

// ---------------- aggregation: feature-split half-row passes ----------------
// Pass covers cols [cb, cb+64): lane = one float of the half-row (256 B/wave,
// coalesced). Working set per pass = 25.6 MB -> better L2 hit rate.
// One wave per node; 8 gather loads in flight.
// If pool != nullptr (last layer): atomicAdd into pool[batch[node]] instead
// of writing H (mean-pool fusion; divide by count happens in out_k).
__global__ __launch_bounds__(256) void aggregate_half_k(
    const float* __restrict__ Y, const int* __restrict__ off,
    const int* __restrict__ srcs, const float* __restrict__ dinv,
    const float* __restrict__ sc, const float* __restrict__ sh,
    const int* __restrict__ batch,
    float* __restrict__ H, float* __restrict__ pool,
    int cb, int dorelu, int n)
{
    const int wid  = threadIdx.x >> 6;
    const int lane = threadIdx.x & 63;
    const int node = blockIdx.x * 4 + wid;
    if (node >= n) return;
    const int beg = off[node], end = off[node + 1];
    const float* Yc = Y + cb + lane;

    float acc  = Yc[node << 7];   // self contribution
    float acc2 = 0.f;

    for (int e = beg; e < end; e += 64) {
        const int nb = min(64, end - e);
        int sidx = (lane < nb) ? srcs[e + lane] : 0;
        int j = 0;
        for (; j + 8 <= nb; j += 8) {
            int s0 = __shfl(sidx, j + 0);
            int s1 = __shfl(sidx, j + 1);
            int s2 = __shfl(sidx, j + 2);
            int s3 = __shfl(sidx, j + 3);
            int s4 = __shfl(sidx, j + 4);
            int s5 = __shfl(sidx, j + 5);
            int s6 = __shfl(sidx, j + 6);
            int s7 = __shfl(sidx, j + 7);
            float v0 = Yc[s0 << 7];
            float v1 = Yc[s1 << 7];
            float v2 = Yc[s2 << 7];
            float v3 = Yc[s3 << 7];
            float v4 = Yc[s4 << 7];
            float v5 = Yc[s5 << 7];
            float v6 = Yc[s6 << 7];
            float v7 = Yc[s7 << 7];
            acc += v0; acc2 += v1; acc += v2; acc2 += v3;
            acc += v4; acc2 += v5; acc += v6; acc2 += v7;
        }
        for (; j < nb; ++j) {
            int s = __shfl(sidx, j);
            acc += Yc[s << 7];
        }
    }
    acc += acc2;

    const float di = dinv[node];
    float o = acc * di * sc[cb + lane] + sh[cb + lane];
    if (dorelu) o = fmaxf(o, 0.f);
    if (pool) {
        atomicAdd(&pool[(batch[node] << 7) + cb + lane], o);
    } else {
        H[(node << 7) + cb + lane] = o;
    }
}

// ---------------- final: pooled mean + 128x40 linear ----------------
__global__ __launch_bounds__(128) void out_k(
    const float* __restrict__ pool, const int* __restrict__ batch,
    const float* __restrict__ lw, const float* __restrict__ lb,
    float* __restrict__ out)
{
    int g = blockIdx.x, f = threadIdx.x;
    int lo = 0, hi = Nn;
    while (lo < hi) { int m = (lo + hi) >> 1; if (batch[m] < g) lo = m + 1; else hi = m; }
    int start = lo;
    hi = Nn;
    while (lo < hi) { int m = (lo + hi) >> 1; if (batch[m] < g + 1) lo = m + 1; else hi = m; }
    int cnt = lo - start;
    float invc = 1.0f / (float)max(cnt, 1);

    __shared__ float pooled[Ff];
    pooled[f] = pool[(g << 7) + f] * invc;
    __syncthreads();
    if (f < Cc) {
        float o = lb[f];
        #pragma unroll 8
        for (int k = 0; k < Ff; ++k) o += pooled[k] * lw[k * Cc + f];
        out[g * Cc + f] = o;
    }
}

// ---------------- launch ----------------
extern "C" void kernel_launch(void* const* d_in, const int* in_sizes, int n_in,
                              void* d_out, int out_size, void* d_ws, size_t ws_size,
                              hipStream_t stream)
{
    const float* x      = (const float*)d_in[0];
    const int*   ei     = (const int*)d_in[1];   // [2,E]: src=ei[0:E), dst=ei[E:2E)
    const int*   batch  = (const int*)d_in[2];
    const float* conv_w = (const float*)d_in[3]; // [3,128,128]
    const float* conv_b = (const float*)d_in[4];
    const float* gamma  = (const float*)d_in[5];
    const float* beta   = (const float*)d_in[6];
    const float* mean   = (const float*)d_in[7];
    const float* var    = (const float*)d_in[8];
    const float* lw     = (const float*)d_in[9];
    const float* lb     = (const float*)d_in[10];
    float* out = (float*)d_out;

    const int* srcp = ei;
    const int* dstp = ei + Ee;

    // workspace layout (deg, cur, pool contiguous -> single memset)
    float* h    = (float*)d_ws;              // N*F
    float* y    = h + (size_t)Nn * Ff;       // N*F
    float* dinv = y + (size_t)Nn * Ff;       // N
    float* sc   = dinv + Nn;                 // 3*F
    float* sh   = sc + 3 * Ff;               // 3*F
    int*   deg  = (int*)(sh + 3 * Ff);       // N
    int*   cur  = deg + Nn;                  // N
    float* pool = (float*)(cur + Nn);        // G*F
    int*   off  = (int*)(pool + Gg * Ff);    // N+1
    int*   csrc = off + (Nn + 1);            // E
    int*   csum = csrc + Ee;                 // NCH
    int*   coff = csum + NCH;                // NCH

    hipMemsetAsync(deg, 0, (2 * (size_t)Nn + Gg * Ff) * sizeof(int), stream);

    prep_scales_k<<<2, 256, 0, stream>>>(conv_b, gamma, beta, mean, var, sc, sh);
    count_edges_k<<<Ee / 256, 256, 0, stream>>>(dstp, deg);
    chunk_sum_k<<<NCH / 256, 256, 0, stream>>>(deg, csum);
    scan_chunks_k<<<1, 256, 0, stream>>>(csum, coff);
    write_offsets_k<<<NCH / 256, 256, 0, stream>>>(deg, coff, off, dinv);
    fill_csr_k<<<Ee / 256, 256, 0, stream>>>(srcp, dstp, off, cur, csrc);

    const int gemm_grid = (Nn + 127) / 128;
    const int agg_grid  = (Nn + 3) / 4;
    for (int l = 0; l < 3; ++l) {
        const float* in = (l == 0) ? x : h;
        gemm_scale_k<<<gemm_grid, 256, 0, stream>>>(in, conv_w + (size_t)l * Ff * Ff,
                                                    dinv, y, Nn);
        float* poolp = (l == 2) ? pool : nullptr;
        for (int p = 0; p < 2; ++p)
            aggregate_half_k<<<agg_grid, 256, 0, stream>>>(
                y, off, csrc, dinv, sc + l * Ff, sh + l * Ff, batch,
                h, poolp, p * 64, (l < 2) ? 1 : 0, Nn);
    }
    out_k<<<Gg, 128, 0, stream>>>(pool, batch, lw, lb, out);
}

// Round 7
// 871.913 us; speedup vs baseline: 1.0461x; 1.0461x over previous
//
#include <hip/hip_runtime.h>

#define Nn 100000
#define Ee 1600000
#define Ff 128
#define Gg 512
#define Cc 40
#define NB 1563   // ceil(Nn/64) buckets of 64 nodes
#define PAD 32    // one counter per 128B line

// ---------------- BN/bias folding: sc/sh per layer-feature ----------------
__global__ void prep_scales_k(const float* __restrict__ conv_b,
                              const float* __restrict__ gamma,
                              const float* __restrict__ beta,
                              const float* __restrict__ mean,
                              const float* __restrict__ var,
                              float* __restrict__ sc, float* __restrict__ sh)
{
    int i = blockIdx.x * blockDim.x + threadIdx.x;
    if (i >= 3 * Ff) return;
    float b = conv_b[i];
    if (i < 2 * Ff) {  // layers 0,1 have BN
        float s = gamma[i] * rsqrtf(var[i] + 1e-5f);
        sc[i] = s;
        sh[i] = (b - mean[i]) * s + beta[i];
    } else {           // layer 2: no BN
        sc[i] = 1.0f;
        sh[i] = b;
    }
}

// ---------------- bucketed CSR build ----------------
__global__ void bucket_count_k(const int* __restrict__ dst, int* __restrict__ bcnt)
{
    int e = blockIdx.x * 256 + threadIdx.x;
    if (e < Ee) atomicAdd(&bcnt[(dst[e] >> 6) * PAD], 1);
}

__global__ void scan_buckets_k(const int* __restrict__ bcnt, int* __restrict__ bktOff,
                               int* __restrict__ off)
{
    __shared__ int tot[256];
    int t = threadIdx.x;
    int v[7]; int s = 0;
    #pragma unroll
    for (int j = 0; j < 7; ++j) {
        int idx = t * 7 + j;
        int val = (idx < NB) ? bcnt[idx * PAD] : 0;
        v[j] = val; s += val;
    }
    tot[t] = s;
    __syncthreads();
    for (int d = 1; d < 256; d <<= 1) {
        int x = (t >= d) ? tot[t - d] : 0;
        __syncthreads();
        tot[t] += x;
        __syncthreads();
    }
    int base = tot[t] - s;  // exclusive prefix
    #pragma unroll
    for (int j = 0; j < 7; ++j) {
        int idx = t * 7 + j;
        if (idx < NB) bktOff[idx] = base;
        base += v[j];
    }
    if (t == 255) { bktOff[NB] = base; off[Nn] = base; }  // base == Ee
}

// staged entry: src | (dstLocal<<17)   (src < 2^17, dstLocal < 64)
__global__ void bucket_fill_k(const int* __restrict__ src, const int* __restrict__ dst,
                              const int* __restrict__ bktOff, int* __restrict__ bcur,
                              int* __restrict__ staged)
{
    int e = blockIdx.x * 256 + threadIdx.x;
    if (e < Ee) {
        int d = dst[e];
        int b = d >> 6;
        int p = atomicAdd(&bcur[b * PAD], 1);
        staged[bktOff[b] + p] = src[e] | ((d & 63) << 17);
    }
}

// One block per bucket: LDS per-node counts -> scan -> off/dinv/csrc.
__global__ __launch_bounds__(256) void bucket_scatter_k(
    const int* __restrict__ staged, const int* __restrict__ bktOff,
    int* __restrict__ off, float* __restrict__ dinv, int* __restrict__ csrc)
{
    __shared__ int cl[64], ol[64], cu[64];
    const int b = blockIdx.x, tid = threadIdx.x;
    const int base = bktOff[b], base2 = bktOff[b + 1];
    if (tid < 64) cl[tid] = 0;
    __syncthreads();
    for (int i = base + tid; i < base2; i += 256)
        atomicAdd(&cl[staged[i] >> 17], 1);
    __syncthreads();
    if (tid == 0) {
        int r = 0;
        #pragma unroll
        for (int l = 0; l < 64; ++l) { ol[l] = r; r += cl[l]; }
    }
    __syncthreads();
    if (tid < 64) {
        int node = b * 64 + tid;
        if (node < Nn) {
            off[node]  = base + ol[tid];
            dinv[node] = rsqrtf((float)cl[tid] + 1.0f);  // +1 self loop
        }
        cu[tid] = 0;
    }
    __syncthreads();
    for (int i = base + tid; i < base2; i += 256) {
        int w = staged[i];
        int l = w >> 17;
        int pos = atomicAdd(&cu[l], 1);
        csrc[base + ol[l] + pos] = w & 0x1FFFF;
    }
}

// ---------------- GEMM v3: Y[r] = (A[r] @ W) * dinv[r] ----------------
// 256 thr = 128 rows x 2 col-halves. Each thread: 1 row, 64 cols.
// W via wave-uniform s_load (SGPR operand of v_fmac). No LDS, no barriers.
__global__ __launch_bounds__(256) void gemm_scale_k(
    const float* __restrict__ A, const float* __restrict__ W,
    const float* __restrict__ dinv, float* __restrict__ Y, int n)
{
    const int tid  = threadIdx.x;
    const int half = __builtin_amdgcn_readfirstlane(tid >> 7);  // wave-uniform
    const int cb   = half * 64;
    const int r    = blockIdx.x * 128 + (tid & 127);
    const int rr   = min(r, n - 1);
    const float4* Ap = (const float4*)(A + ((size_t)rr << 7));
    const float*  Wp = W + cb;

    float acc[64];
    #pragma unroll
    for (int c = 0; c < 64; ++c) acc[c] = 0.f;

    for (int kc = 0; kc < 4; ++kc) {          // k in chunks of 32
        float4 a[8];
        #pragma unroll
        for (int i = 0; i < 8; ++i) a[i] = Ap[kc * 8 + i];
        const float* af = reinterpret_cast<const float*>(a);
        #pragma unroll
        for (int kk = 0; kk < 32; ++kk) {
            const float av = af[kk];
            const float* wr = Wp + (kc * 32 + kk) * Ff;    // uniform -> s_load
            #pragma unroll
            for (int c = 0; c < 64; ++c)
                acc[c] = fmaf(av, wr[c], acc[c]);
        }
    }

    if (r < n) {
        const float di = dinv[r];
        float* yp = Y + ((size_t)r << 7) + cb;
        #pragma unroll
        for (int c = 0; c < 64; c += 4)
            *(float4*)(yp + c) = make_float4(acc[c] * di, acc[c + 1] * di,
                                             acc[c + 2] * di, acc[c + 3] * di);
    }
}

// ---------------- aggregation: one wave per node, full row (float2/lane) ----
// H[i] = act( dinv[i] * (sum_in Y[src] + Y[i]) * sc + sh )
// Last layer (pool != nullptr): atomicAdd into pool[batch[i]] (mean in out_k).
__global__ __launch_bounds__(256) void aggregate_k(
    const float* __restrict__ Y, const int* __restrict__ off,
    const int* __restrict__ srcs, const float* __restrict__ dinv,
    const float* __restrict__ sc, const float* __restrict__ sh,
    const int* __restrict__ batch,
    float* __restrict__ H, float* __restrict__ pool, int dorelu, int n)
{
    int wid  = threadIdx.x >> 6;
    int lane = threadIdx.x & 63;
    int node = blockIdx.x * 4 + wid;
    if (node >= n) return;
    int beg = off[node], end = off[node + 1];
    int c = lane * 2;

    float2 self = *(const float2*)(Y + ((size_t)node << 7) + c);
    float ax = self.x, ay = self.y;
    float bx = 0.f,    by = 0.f;

    for (int e = beg; e < end; e += 64) {
        int nb = min(64, end - e);
        int sidx = (lane < nb) ? srcs[e + lane] : 0;
        int j = 0;
        for (; j + 4 <= nb; j += 4) {
            int s0 = __shfl(sidx, j);
            int s1 = __shfl(sidx, j + 1);
            int s2 = __shfl(sidx, j + 2);
            int s3 = __shfl(sidx, j + 3);
            float2 v0 = *(const float2*)(Y + ((size_t)s0 << 7) + c);
            float2 v1 = *(const float2*)(Y + ((size_t)s1 << 7) + c);
            float2 v2 = *(const float2*)(Y + ((size_t)s2 << 7) + c);
            float2 v3 = *(const float2*)(Y + ((size_t)s3 << 7) + c);
            ax += v0.x; ay += v0.y; bx += v1.x; by += v1.y;
            ax += v2.x; ay += v2.y; bx += v3.x; by += v3.y;
        }
        for (; j < nb; ++j) {
            int s0 = __shfl(sidx, j);
            float2 v0 = *(const float2*)(Y + ((size_t)s0 << 7) + c);
            ax += v0.x; ay += v0.y;
        }
    }
    float di = dinv[node];
    float2 scv = *(const float2*)(sc + c);
    float2 shv = *(const float2*)(sh + c);
    float ox = (ax + bx) * di * scv.x + shv.x;
    float oy = (ay + by) * di * scv.y + shv.y;
    if (dorelu) { ox = fmaxf(ox, 0.f); oy = fmaxf(oy, 0.f); }
    if (pool) {
        float* pp = pool + ((size_t)batch[node] << 7) + c;
        atomicAdd(pp,     ox);
        atomicAdd(pp + 1, oy);
    } else {
        *(float2*)(H + ((size_t)node << 7) + c) = make_float2(ox, oy);
    }
}

// ---------------- final: pooled mean + 128x40 linear ----------------
__global__ __launch_bounds__(128) void out_k(
    const float* __restrict__ pool, const int* __restrict__ batch,
    const float* __restrict__ lw, const float* __restrict__ lb,
    float* __restrict__ out)
{
    int g = blockIdx.x, f = threadIdx.x;
    int lo = 0, hi = Nn;
    while (lo < hi) { int m = (lo + hi) >> 1; if (batch[m] < g) lo = m + 1; else hi = m; }
    int start = lo;
    hi = Nn;
    while (lo < hi) { int m = (lo + hi) >> 1; if (batch[m] < g + 1) lo = m + 1; else hi = m; }
    int cnt = lo - start;
    float invc = 1.0f / (float)max(cnt, 1);

    __shared__ float pooled[Ff];
    pooled[f] = pool[(g << 7) + f] * invc;
    __syncthreads();
    if (f < Cc) {
        float o = lb[f];
        #pragma unroll 8
        for (int k = 0; k < Ff; ++k) o += pooled[k] * lw[k * Cc + f];
        out[g * Cc + f] = o;
    }
}

// ---------------- launch ----------------
extern "C" void kernel_launch(void* const* d_in, const int* in_sizes, int n_in,
                              void* d_out, int out_size, void* d_ws, size_t ws_size,
                              hipStream_t stream)
{
    const float* x      = (const float*)d_in[0];
    const int*   ei     = (const int*)d_in[1];   // [2,E]: src=ei[0:E), dst=ei[E:2E)
    const int*   batch  = (const int*)d_in[2];
    const float* conv_w = (const float*)d_in[3]; // [3,128,128]
    const float* conv_b = (const float*)d_in[4];
    const float* gamma  = (const float*)d_in[5];
    const float* beta   = (const float*)d_in[6];
    const float* mean   = (const float*)d_in[7];
    const float* var    = (const float*)d_in[8];
    const float* lw     = (const float*)d_in[9];
    const float* lb     = (const float*)d_in[10];
    float* out = (float*)d_out;

    const int* srcp = ei;
    const int* dstp = ei + Ee;

    // workspace layout
    float* h      = (float*)d_ws;              // N*F   (also aliased as staged)
    float* y      = h + (size_t)Nn * Ff;       // N*F
    float* dinv   = y + (size_t)Nn * Ff;       // N
    float* sc     = dinv + Nn;                 // 3*F
    float* sh     = sc + 3 * Ff;               // 3*F
    int*   bcnt   = (int*)(sh + 3 * Ff);       // NB*PAD
    int*   bcur   = bcnt + NB * PAD;           // NB*PAD
    float* pool   = (float*)(bcur + NB * PAD); // G*F
    int*   off    = (int*)(pool + Gg * Ff);    // N+1
    int*   csrc   = off + (Nn + 1);            // E
    int*   bktOff = csrc + Ee;                 // NB+1
    int*   staged = (int*)h;                   // E (dead before aggregate L0 writes h)

    // zero bcnt | bcur | pool in one shot (contiguous)
    hipMemsetAsync(bcnt, 0, (size_t)(2 * NB * PAD + Gg * Ff) * sizeof(int), stream);

    prep_scales_k<<<2, 256, 0, stream>>>(conv_b, gamma, beta, mean, var, sc, sh);
    bucket_count_k<<<Ee / 256, 256, 0, stream>>>(dstp, bcnt);
    scan_buckets_k<<<1, 256, 0, stream>>>(bcnt, bktOff, off);
    bucket_fill_k<<<Ee / 256, 256, 0, stream>>>(srcp, dstp, bktOff, bcur, staged);
    bucket_scatter_k<<<NB, 256, 0, stream>>>(staged, bktOff, off, dinv, csrc);

    const int gemm_grid = (Nn + 127) / 128;
    const int agg_grid  = (Nn + 3) / 4;
    for (int l = 0; l < 3; ++l) {
        const float* in = (l == 0) ? x : h;
        gemm_scale_k<<<gemm_grid, 256, 0, stream>>>(in, conv_w + (size_t)l * Ff * Ff,
                                                    dinv, y, Nn);
        aggregate_k<<<agg_grid, 256, 0, stream>>>(
            y, off, csrc, dinv, sc + l * Ff, sh + l * Ff, batch,
            h, (l == 2) ? pool : nullptr, (l < 2) ? 1 : 0, Nn);
    }
    out_k<<<Gg, 128, 0, stream>>>(pool, batch, lw, lb, out);
}

// Round 9
// 834.037 us; speedup vs baseline: 1.0936x; 1.0454x over previous
//
#include <hip/hip_runtime.h>

#define Nn 100000
#define Ee 1600000
#define Ff 128
#define Gg 512
#define Cc 40
#define NB 1563   // ceil(Nn/64) buckets of 64 nodes
#define PAD 32    // one counter per 128B line

// ---------------- BN/bias folding: sc/sh per layer-feature ----------------
__global__ void prep_scales_k(const float* __restrict__ conv_b,
                              const float* __restrict__ gamma,
                              const float* __restrict__ beta,
                              const float* __restrict__ mean,
                              const float* __restrict__ var,
                              float* __restrict__ sc, float* __restrict__ sh)
{
    int i = blockIdx.x * blockDim.x + threadIdx.x;
    if (i >= 3 * Ff) return;
    float b = conv_b[i];
    if (i < 2 * Ff) {  // layers 0,1 have BN
        float s = gamma[i] * rsqrtf(var[i] + 1e-5f);
        sc[i] = s;
        sh[i] = (b - mean[i]) * s + beta[i];
    } else {           // layer 2: no BN
        sc[i] = 1.0f;
        sh[i] = b;
    }
}

// ---------------- bucketed CSR build ----------------
__global__ void bucket_count_k(const int* __restrict__ dst, int* __restrict__ bcnt)
{
    int e = blockIdx.x * 256 + threadIdx.x;
    if (e < Ee) atomicAdd(&bcnt[(dst[e] >> 6) * PAD], 1);
}

__global__ void scan_buckets_k(const int* __restrict__ bcnt, int* __restrict__ bktOff,
                               int* __restrict__ off)
{
    __shared__ int tot[256];
    int t = threadIdx.x;
    int v[7]; int s = 0;
    #pragma unroll
    for (int j = 0; j < 7; ++j) {
        int idx = t * 7 + j;
        int val = (idx < NB) ? bcnt[idx * PAD] : 0;
        v[j] = val; s += val;
    }
    tot[t] = s;
    __syncthreads();
    for (int d = 1; d < 256; d <<= 1) {
        int x = (t >= d) ? tot[t - d] : 0;
        __syncthreads();
        tot[t] += x;
        __syncthreads();
    }
    int base = tot[t] - s;  // exclusive prefix
    #pragma unroll
    for (int j = 0; j < 7; ++j) {
        int idx = t * 7 + j;
        if (idx < NB) bktOff[idx] = base;
        base += v[j];
    }
    if (t == 255) { bktOff[NB] = base; off[Nn] = base; }  // base == Ee
}

// staged entry: src | (dstLocal<<17)   (src < 2^17, dstLocal < 64)
__global__ void bucket_fill_k(const int* __restrict__ src, const int* __restrict__ dst,
                              const int* __restrict__ bktOff, int* __restrict__ bcur,
                              int* __restrict__ staged)
{
    int e = blockIdx.x * 256 + threadIdx.x;
    if (e < Ee) {
        int d = dst[e];
        int b = d >> 6;
        int p = atomicAdd(&bcur[b * PAD], 1);
        staged[bktOff[b] + p] = src[e] | ((d & 63) << 17);
    }
}

// One block per bucket: LDS per-node counts -> scan -> off/dinv/csrc.
__global__ __launch_bounds__(256) void bucket_scatter_k(
    const int* __restrict__ staged, const int* __restrict__ bktOff,
    int* __restrict__ off, float* __restrict__ dinv, int* __restrict__ csrc)
{
    __shared__ int cl[64], ol[64], cu[64];
    const int b = blockIdx.x, tid = threadIdx.x;
    const int base = bktOff[b], base2 = bktOff[b + 1];
    if (tid < 64) cl[tid] = 0;
    __syncthreads();
    for (int i = base + tid; i < base2; i += 256)
        atomicAdd(&cl[staged[i] >> 17], 1);
    __syncthreads();
    if (tid == 0) {
        int r = 0;
        #pragma unroll
        for (int l = 0; l < 64; ++l) { ol[l] = r; r += cl[l]; }
    }
    __syncthreads();
    if (tid < 64) {
        int node = b * 64 + tid;
        if (node < Nn) {
            off[node]  = base + ol[tid];
            dinv[node] = rsqrtf((float)cl[tid] + 1.0f);  // +1 self loop
        }
        cu[tid] = 0;
    }
    __syncthreads();
    for (int i = base + tid; i < base2; i += 256) {
        int w = staged[i];
        int l = w >> 17;
        int pos = atomicAdd(&cu[l], 1);
        csrc[base + ol[l] + pos] = w & 0x1FFFF;
    }
}

// ---------------- GEMM v3: Y[r] = (A[r] @ W) * dinv[r] ----------------
// 256 thr = 128 rows x 2 col-halves. Each thread: 1 row, 64 cols.
// W via wave-uniform s_load (SGPR operand of v_fmac). No LDS, no barriers.
__global__ __launch_bounds__(256) void gemm_scale_k(
    const float* __restrict__ A, const float* __restrict__ W,
    const float* __restrict__ dinv, float* __restrict__ Y, int n)
{
    const int tid  = threadIdx.x;
    const int half = __builtin_amdgcn_readfirstlane(tid >> 7);  // wave-uniform
    const int cb   = half * 64;
    const int r    = blockIdx.x * 128 + (tid & 127);
    const int rr   = min(r, n - 1);
    const float4* Ap = (const float4*)(A + ((size_t)rr << 7));
    const float*  Wp = W + cb;

    float acc[64];
    #pragma unroll
    for (int c = 0; c < 64; ++c) acc[c] = 0.f;

    for (int kc = 0; kc < 4; ++kc) {          // k in chunks of 32
        float4 a[8];
        #pragma unroll
        for (int i = 0; i < 8; ++i) a[i] = Ap[kc * 8 + i];
        const float* af = reinterpret_cast<const float*>(a);
        #pragma unroll
        for (int kk = 0; kk < 32; ++kk) {
            const float av = af[kk];
            const float* wr = Wp + (kc * 32 + kk) * Ff;    // uniform -> s_load
            #pragma unroll
            for (int c = 0; c < 64; ++c)
                acc[c] = fmaf(av, wr[c], acc[c]);
        }
    }

    if (r < n) {
        const float di = dinv[r];
        float* yp = Y + ((size_t)r << 7) + cb;
        #pragma unroll
        for (int c = 0; c < 64; c += 4)
            *(float4*)(yp + c) = make_float4(acc[c] * di, acc[c + 1] * di,
                                             acc[c + 2] * di, acc[c + 3] * di);
    }
}

// ---------------- aggregation: one wave per node (round-2 exact form) ------
// H[i] = act( dinv[i] * (sum_in Y[src] + Y[i]) * sc + sh )
__global__ __launch_bounds__(256) void aggregate_k(
    const float* __restrict__ Y, const int* __restrict__ off,
    const int* __restrict__ srcs, const float* __restrict__ dinv,
    const float* __restrict__ sc, const float* __restrict__ sh,
    float* __restrict__ H, int dorelu, int n)
{
    int wid  = threadIdx.x >> 6;
    int lane = threadIdx.x & 63;
    int node = blockIdx.x * 4 + wid;
    if (node >= n) return;
    int beg = off[node], end = off[node + 1];
    int c = lane * 2;

    float2 self = *(const float2*)(Y + (size_t)node * Ff + c);
    float ax = self.x, ay = self.y;   // acc pair A
    float bx = 0.f,    by = 0.f;      // acc pair B (break dep chain)

    for (int e = beg; e < end; e += 64) {
        int nb = min(64, end - e);
        int sidx = (lane < nb) ? srcs[e + lane] : 0;
        int j = 0;
        for (; j + 4 <= nb; j += 4) {
            int s0 = __shfl(sidx, j);
            int s1 = __shfl(sidx, j + 1);
            int s2 = __shfl(sidx, j + 2);
            int s3 = __shfl(sidx, j + 3);
            float2 v0 = *(const float2*)(Y + (size_t)s0 * Ff + c);
            float2 v1 = *(const float2*)(Y + (size_t)s1 * Ff + c);
            float2 v2 = *(const float2*)(Y + (size_t)s2 * Ff + c);
            float2 v3 = *(const float2*)(Y + (size_t)s3 * Ff + c);
            ax += v0.x; ay += v0.y; bx += v1.x; by += v1.y;
            ax += v2.x; ay += v2.y; bx += v3.x; by += v3.y;
        }
        for (; j < nb; ++j) {
            int s0 = __shfl(sidx, j);
            float2 v0 = *(const float2*)(Y + (size_t)s0 * Ff + c);
            ax += v0.x; ay += v0.y;
        }
    }
    float di = dinv[node];
    float2 scv = *(const float2*)(sc + c);
    float2 shv = *(const float2*)(sh + c);
    float ox = (ax + bx) * di * scv.x + shv.x;
    float oy = (ay + by) * di * scv.y + shv.y;
    if (dorelu) { ox = fmaxf(ox, 0.f); oy = fmaxf(oy, 0.f); }
    *(float2*)(H + (size_t)node * Ff + c) = make_float2(ox, oy);
}

// ---------------- mean-pool (batch sorted -> binary search) + linear ----------------
__global__ __launch_bounds__(128) void pool_linear_k(
    const float* __restrict__ H, const int* __restrict__ batch,
    const float* __restrict__ lw, const float* __restrict__ lb,
    float* __restrict__ out)
{
    int g = blockIdx.x, f = threadIdx.x;
    int lo = 0, hi = Nn;
    while (lo < hi) { int m = (lo + hi) >> 1; if (batch[m] < g) lo = m + 1; else hi = m; }
    int start = lo;
    hi = Nn;
    while (lo < hi) { int m = (lo + hi) >> 1; if (batch[m] < g + 1) lo = m + 1; else hi = m; }
    int end = lo;

    float a0 = 0.f, a1 = 0.f, a2 = 0.f, a3 = 0.f;
    int i = start;
    for (; i + 4 <= end; i += 4) {
        a0 += H[(size_t)(i + 0) * Ff + f];
        a1 += H[(size_t)(i + 1) * Ff + f];
        a2 += H[(size_t)(i + 2) * Ff + f];
        a3 += H[(size_t)(i + 3) * Ff + f];
    }
    for (; i < end; ++i) a0 += H[(size_t)i * Ff + f];
    int cnt = end - start;
    __shared__ float pooled[Ff];
    pooled[f] = ((a0 + a1) + (a2 + a3)) / (float)max(cnt, 1);
    __syncthreads();
    if (f < Cc) {
        float o = lb[f];
        #pragma unroll 8
        for (int k = 0; k < Ff; ++k) o += pooled[k] * lw[k * Cc + f];
        out[g * Cc + f] = o;
    }
}

// ---------------- launch ----------------
extern "C" void kernel_launch(void* const* d_in, const int* in_sizes, int n_in,
                              void* d_out, int out_size, void* d_ws, size_t ws_size,
                              hipStream_t stream)
{
    const float* x      = (const float*)d_in[0];
    const int*   ei     = (const int*)d_in[1];   // [2,E]: src=ei[0:E), dst=ei[E:2E)
    const int*   batch  = (const int*)d_in[2];
    const float* conv_w = (const float*)d_in[3]; // [3,128,128]
    const float* conv_b = (const float*)d_in[4];
    const float* gamma  = (const float*)d_in[5];
    const float* beta   = (const float*)d_in[6];
    const float* mean   = (const float*)d_in[7];
    const float* var    = (const float*)d_in[8];
    const float* lw     = (const float*)d_in[9];
    const float* lb     = (const float*)d_in[10];
    float* out = (float*)d_out;

    const int* srcp = ei;
    const int* dstp = ei + Ee;

    // workspace layout
    float* h      = (float*)d_ws;              // N*F
    float* y      = h + (size_t)Nn * Ff;       // N*F   (first 6.4MB aliased as staged)
    float* dinv   = y + (size_t)Nn * Ff;       // N
    float* sc     = dinv + Nn;                 // 3*F
    float* sh     = sc + 3 * Ff;               // 3*F
    int*   bcnt   = (int*)(sh + 3 * Ff);       // NB*PAD
    int*   bcur   = bcnt + NB * PAD;           // NB*PAD
    int*   off    = bcur + NB * PAD;           // N+1
    int*   csrc   = off + (Nn + 1);            // E
    int*   bktOff = csrc + Ee;                 // NB+1
    int*   staged = (int*)y;                   // E (consumed before gemm l=0 writes y)

    // zero bcnt | bcur in one shot (contiguous)
    hipMemsetAsync(bcnt, 0, (size_t)(2 * NB * PAD) * sizeof(int), stream);

    prep_scales_k<<<2, 256, 0, stream>>>(conv_b, gamma, beta, mean, var, sc, sh);
    bucket_count_k<<<Ee / 256, 256, 0, stream>>>(dstp, bcnt);
    scan_buckets_k<<<1, 256, 0, stream>>>(bcnt, bktOff, off);
    bucket_fill_k<<<Ee / 256, 256, 0, stream>>>(srcp, dstp, bktOff, bcur, staged);
    bucket_scatter_k<<<NB, 256, 0, stream>>>(staged, bktOff, off, dinv, csrc);

    const int gemm_grid = (Nn + 127) / 128;
    const int agg_grid  = (Nn + 3) / 4;
    for (int l = 0; l < 3; ++l) {
        const float* in = (l == 0) ? x : h;
        gemm_scale_k<<<gemm_grid, 256, 0, stream>>>(in, conv_w + (size_t)l * Ff * Ff,
                                                    dinv, y, Nn);
        aggregate_k<<<agg_grid, 256, 0, stream>>>(
            y, off, csrc, dinv, sc + l * Ff, sh + l * Ff,
            h, (l < 2) ? 1 : 0, Nn);
    }
    pool_linear_k<<<Gg, 128, 0, stream>>>(h, batch, lw, lb, out);
}

// Round 10
// 733.233 us; speedup vs baseline: 1.2440x; 1.1375x over previous
//
#include <hip/hip_runtime.h>

#define Nn 100000
#define Ee 1600000
#define Ff 128
#define Gg 512
#define Cc 40
#define NB 1563   // ceil(Nn/64) buckets of 64 nodes
#define PAD 32    // one counter per 128B line
#define FB 256    // fill/count blocks
#define EPB 6250  // edges per block (FB*EPB == Ee)

// ---------------- BN/bias folding: sc/sh per layer-feature ----------------
__global__ void prep_scales_k(const float* __restrict__ conv_b,
                              const float* __restrict__ gamma,
                              const float* __restrict__ beta,
                              const float* __restrict__ mean,
                              const float* __restrict__ var,
                              float* __restrict__ sc, float* __restrict__ sh)
{
    int i = blockIdx.x * blockDim.x + threadIdx.x;
    if (i >= 3 * Ff) return;
    float b = conv_b[i];
    if (i < 2 * Ff) {  // layers 0,1 have BN
        float s = gamma[i] * rsqrtf(var[i] + 1e-5f);
        sc[i] = s;
        sh[i] = (b - mean[i]) * s + beta[i];
    } else {           // layer 2: no BN
        sc[i] = 1.0f;
        sh[i] = b;
    }
}

// ---------------- bucketed CSR build (LDS-batched atomics) ----------------
// v2: per-block LDS histogram, then one global atomic per (block,bucket).
__global__ __launch_bounds__(1024) void bucket_count_k(
    const int* __restrict__ dst, int* __restrict__ bcnt)
{
    __shared__ int cnt[NB];
    const int t = threadIdx.x;
    for (int b = t; b < NB; b += 1024) cnt[b] = 0;
    __syncthreads();
    const int e0 = blockIdx.x * EPB;
    #pragma unroll
    for (int j = 0; j < 7; ++j) {
        int e = e0 + t + j * 1024;
        if (e < e0 + EPB) atomicAdd(&cnt[dst[e] >> 6], 1);
    }
    __syncthreads();
    for (int b = t; b < NB; b += 1024) {
        int c = cnt[b];
        if (c) atomicAdd(&bcnt[b * PAD], c);
    }
}

__global__ void scan_buckets_k(const int* __restrict__ bcnt, int* __restrict__ bktOff,
                               int* __restrict__ off)
{
    __shared__ int tot[256];
    int t = threadIdx.x;
    int v[7]; int s = 0;
    #pragma unroll
    for (int j = 0; j < 7; ++j) {
        int idx = t * 7 + j;
        int val = (idx < NB) ? bcnt[idx * PAD] : 0;
        v[j] = val; s += val;
    }
    tot[t] = s;
    __syncthreads();
    for (int d = 1; d < 256; d <<= 1) {
        int x = (t >= d) ? tot[t - d] : 0;
        __syncthreads();
        tot[t] += x;
        __syncthreads();
    }
    int base = tot[t] - s;  // exclusive prefix
    #pragma unroll
    for (int j = 0; j < 7; ++j) {
        int idx = t * 7 + j;
        if (idx < NB) bktOff[idx] = base;
        base += v[j];
    }
    if (t == 255) { bktOff[NB] = base; off[Nn] = base; }  // base == Ee
}

// v2: 3-phase range reservation. staged entry: src | (dstLocal<<17)
__global__ __launch_bounds__(1024) void bucket_fill_k(
    const int* __restrict__ src, const int* __restrict__ dst,
    const int* __restrict__ bktOff, int* __restrict__ bcur,
    int* __restrict__ staged)
{
    __shared__ int cnt[NB];
    __shared__ int gb[NB];
    const int t = threadIdx.x;
    for (int b = t; b < NB; b += 1024) cnt[b] = 0;
    __syncthreads();
    const int e0 = blockIdx.x * EPB;
    int bb[7], lp[7], pl[7];
    #pragma unroll
    for (int j = 0; j < 7; ++j) {
        int e = e0 + t + j * 1024;
        bb[j] = -1;
        if (e < e0 + EPB) {
            int d = dst[e];
            int b = d >> 6;
            bb[j] = b;
            lp[j] = atomicAdd(&cnt[b], 1);
            pl[j] = src[e] | ((d & 63) << 17);
        }
    }
    __syncthreads();
    for (int b = t; b < NB; b += 1024) {
        int c = cnt[b];
        gb[b] = c ? atomicAdd(&bcur[b * PAD], c) : 0;
    }
    __syncthreads();
    #pragma unroll
    for (int j = 0; j < 7; ++j) {
        int b = bb[j];
        if (b >= 0) staged[bktOff[b] + gb[b] + lp[j]] = pl[j];
    }
}

// One block per bucket: LDS per-node counts -> scan -> off/dinv/csrc.
__global__ __launch_bounds__(256) void bucket_scatter_k(
    const int* __restrict__ staged, const int* __restrict__ bktOff,
    int* __restrict__ off, float* __restrict__ dinv, int* __restrict__ csrc)
{
    __shared__ int cl[64], ol[64], cu[64];
    const int b = blockIdx.x, tid = threadIdx.x;
    const int base = bktOff[b], base2 = bktOff[b + 1];
    if (tid < 64) cl[tid] = 0;
    __syncthreads();
    for (int i = base + tid; i < base2; i += 256)
        atomicAdd(&cl[staged[i] >> 17], 1);
    __syncthreads();
    if (tid == 0) {
        int r = 0;
        #pragma unroll
        for (int l = 0; l < 64; ++l) { ol[l] = r; r += cl[l]; }
    }
    __syncthreads();
    if (tid < 64) {
        int node = b * 64 + tid;
        if (node < Nn) {
            off[node]  = base + ol[tid];
            dinv[node] = rsqrtf((float)cl[tid] + 1.0f);  // +1 self loop
        }
        cu[tid] = 0;
    }
    __syncthreads();
    for (int i = base + tid; i < base2; i += 256) {
        int w = staged[i];
        int l = w >> 17;
        int pos = atomicAdd(&cu[l], 1);
        csrc[base + ol[l] + pos] = w & 0x1FFFF;
    }
}

// ---------------- GEMM v3: Y[r] = (A[r] @ W) * dinv[r] ----------------
// 256 thr = 128 rows x 2 col-halves. Each thread: 1 row, 64 cols.
// W via wave-uniform s_load (SGPR operand of v_fmac). No LDS, no barriers.
__global__ __launch_bounds__(256) void gemm_scale_k(
    const float* __restrict__ A, const float* __restrict__ W,
    const float* __restrict__ dinv, float* __restrict__ Y, int n)
{
    const int tid  = threadIdx.x;
    const int half = __builtin_amdgcn_readfirstlane(tid >> 7);  // wave-uniform
    const int cb   = half * 64;
    const int r    = blockIdx.x * 128 + (tid & 127);
    const int rr   = min(r, n - 1);
    const float4* Ap = (const float4*)(A + ((size_t)rr << 7));
    const float*  Wp = W + cb;

    float acc[64];
    #pragma unroll
    for (int c = 0; c < 64; ++c) acc[c] = 0.f;

    for (int kc = 0; kc < 4; ++kc) {          // k in chunks of 32
        float4 a[8];
        #pragma unroll
        for (int i = 0; i < 8; ++i) a[i] = Ap[kc * 8 + i];
        const float* af = reinterpret_cast<const float*>(a);
        #pragma unroll
        for (int kk = 0; kk < 32; ++kk) {
            const float av = af[kk];
            const float* wr = Wp + (kc * 32 + kk) * Ff;    // uniform -> s_load
            #pragma unroll
            for (int c = 0; c < 64; ++c)
                acc[c] = fmaf(av, wr[c], acc[c]);
        }
    }

    if (r < n) {
        const float di = dinv[r];
        float* yp = Y + ((size_t)r << 7) + cb;
        #pragma unroll
        for (int c = 0; c < 64; c += 4)
            *(float4*)(yp + c) = make_float4(acc[c] * di, acc[c + 1] * di,
                                             acc[c + 2] * di, acc[c + 3] * di);
    }
}

// ---------------- aggregation: one wave per node (round-2 exact form) ------
// H[i] = act( dinv[i] * (sum_in Y[src] + Y[i]) * sc + sh )
__global__ __launch_bounds__(256) void aggregate_k(
    const float* __restrict__ Y, const int* __restrict__ off,
    const int* __restrict__ srcs, const float* __restrict__ dinv,
    const float* __restrict__ sc, const float* __restrict__ sh,
    float* __restrict__ H, int dorelu, int n)
{
    int wid  = threadIdx.x >> 6;
    int lane = threadIdx.x & 63;
    int node = blockIdx.x * 4 + wid;
    if (node >= n) return;
    int beg = off[node], end = off[node + 1];
    int c = lane * 2;

    float2 self = *(const float2*)(Y + (size_t)node * Ff + c);
    float ax = self.x, ay = self.y;   // acc pair A
    float bx = 0.f,    by = 0.f;      // acc pair B (break dep chain)

    for (int e = beg; e < end; e += 64) {
        int nb = min(64, end - e);
        int sidx = (lane < nb) ? srcs[e + lane] : 0;
        int j = 0;
        for (; j + 4 <= nb; j += 4) {
            int s0 = __shfl(sidx, j);
            int s1 = __shfl(sidx, j + 1);
            int s2 = __shfl(sidx, j + 2);
            int s3 = __shfl(sidx, j + 3);
            float2 v0 = *(const float2*)(Y + (size_t)s0 * Ff + c);
            float2 v1 = *(const float2*)(Y + (size_t)s1 * Ff + c);
            float2 v2 = *(const float2*)(Y + (size_t)s2 * Ff + c);
            float2 v3 = *(const float2*)(Y + (size_t)s3 * Ff + c);
            ax += v0.x; ay += v0.y; bx += v1.x; by += v1.y;
            ax += v2.x; ay += v2.y; bx += v3.x; by += v3.y;
        }
        for (; j < nb; ++j) {
            int s0 = __shfl(sidx, j);
            float2 v0 = *(const float2*)(Y + (size_t)s0 * Ff + c);
            ax += v0.x; ay += v0.y;
        }
    }
    float di = dinv[node];
    float2 scv = *(const float2*)(sc + c);
    float2 shv = *(const float2*)(sh + c);
    float ox = (ax + bx) * di * scv.x + shv.x;
    float oy = (ay + by) * di * scv.y + shv.y;
    if (dorelu) { ox = fmaxf(ox, 0.f); oy = fmaxf(oy, 0.f); }
    *(float2*)(H + (size_t)node * Ff + c) = make_float2(ox, oy);
}

// ---------------- mean-pool (batch sorted -> binary search) + linear ----------------
__global__ __launch_bounds__(128) void pool_linear_k(
    const float* __restrict__ H, const int* __restrict__ batch,
    const float* __restrict__ lw, const float* __restrict__ lb,
    float* __restrict__ out)
{
    int g = blockIdx.x, f = threadIdx.x;
    int lo = 0, hi = Nn;
    while (lo < hi) { int m = (lo + hi) >> 1; if (batch[m] < g) lo = m + 1; else hi = m; }
    int start = lo;
    hi = Nn;
    while (lo < hi) { int m = (lo + hi) >> 1; if (batch[m] < g + 1) lo = m + 1; else hi = m; }
    int end = lo;

    float a0 = 0.f, a1 = 0.f, a2 = 0.f, a3 = 0.f;
    int i = start;
    for (; i + 4 <= end; i += 4) {
        a0 += H[(size_t)(i + 0) * Ff + f];
        a1 += H[(size_t)(i + 1) * Ff + f];
        a2 += H[(size_t)(i + 2) * Ff + f];
        a3 += H[(size_t)(i + 3) * Ff + f];
    }
    for (; i < end; ++i) a0 += H[(size_t)i * Ff + f];
    int cnt = end - start;
    __shared__ float pooled[Ff];
    pooled[f] = ((a0 + a1) + (a2 + a3)) / (float)max(cnt, 1);
    __syncthreads();
    if (f < Cc) {
        float o = lb[f];
        #pragma unroll 8
        for (int k = 0; k < Ff; ++k) o += pooled[k] * lw[k * Cc + f];
        out[g * Cc + f] = o;
    }
}

// ---------------- launch ----------------
extern "C" void kernel_launch(void* const* d_in, const int* in_sizes, int n_in,
                              void* d_out, int out_size, void* d_ws, size_t ws_size,
                              hipStream_t stream)
{
    const float* x      = (const float*)d_in[0];
    const int*   ei     = (const int*)d_in[1];   // [2,E]: src=ei[0:E), dst=ei[E:2E)
    const int*   batch  = (const int*)d_in[2];
    const float* conv_w = (const float*)d_in[3]; // [3,128,128]
    const float* conv_b = (const float*)d_in[4];
    const float* gamma  = (const float*)d_in[5];
    const float* beta   = (const float*)d_in[6];
    const float* mean   = (const float*)d_in[7];
    const float* var    = (const float*)d_in[8];
    const float* lw     = (const float*)d_in[9];
    const float* lb     = (const float*)d_in[10];
    float* out = (float*)d_out;

    const int* srcp = ei;
    const int* dstp = ei + Ee;

    // workspace layout
    float* h      = (float*)d_ws;              // N*F
    float* y      = h + (size_t)Nn * Ff;       // N*F   (first 6.4MB aliased as staged)
    float* dinv   = y + (size_t)Nn * Ff;       // N
    float* sc     = dinv + Nn;                 // 3*F
    float* sh     = sc + 3 * Ff;               // 3*F
    int*   bcnt   = (int*)(sh + 3 * Ff);       // NB*PAD
    int*   bcur   = bcnt + NB * PAD;           // NB*PAD
    int*   off    = bcur + NB * PAD;           // N+1
    int*   csrc   = off + (Nn + 1);            // E
    int*   bktOff = csrc + Ee;                 // NB+1
    int*   staged = (int*)y;                   // E (consumed before gemm l=0 writes y)

    // zero bcnt | bcur in one shot (contiguous)
    hipMemsetAsync(bcnt, 0, (size_t)(2 * NB * PAD) * sizeof(int), stream);

    prep_scales_k<<<2, 256, 0, stream>>>(conv_b, gamma, beta, mean, var, sc, sh);
    bucket_count_k<<<FB, 1024, 0, stream>>>(dstp, bcnt);
    scan_buckets_k<<<1, 256, 0, stream>>>(bcnt, bktOff, off);
    bucket_fill_k<<<FB, 1024, 0, stream>>>(srcp, dstp, bktOff, bcur, staged);
    bucket_scatter_k<<<NB, 256, 0, stream>>>(staged, bktOff, off, dinv, csrc);

    const int gemm_grid = (Nn + 127) / 128;
    const int agg_grid  = (Nn + 3) / 4;
    for (int l = 0; l < 3; ++l) {
        const float* in = (l == 0) ? x : h;
        gemm_scale_k<<<gemm_grid, 256, 0, stream>>>(in, conv_w + (size_t)l * Ff * Ff,
                                                    dinv, y, Nn);
        aggregate_k<<<agg_grid, 256, 0, stream>>>(
            y, off, csrc, dinv, sc + l * Ff, sh + l * Ff,
            h, (l < 2) ? 1 : 0, Nn);
    }
    pool_linear_k<<<Gg, 128, 0, stream>>>(h, batch, lw, lb, out);
}